// Round 4
// baseline (335.838 us; speedup 1.0000x reference)
//
#include <hip/hip_runtime.h>
#include <math.h>

#define NTOK 50257
#define NHID 1024
#define NPC  225
#define NCLS 224
#define BATCH 1024

// ws: float ptop[1024] at offset 0
// ---------------------------------------------------------------------------
// K1: top logits + softmax -> ptop[s]. 8 samples/block, 128 blocks, 512 thr.
// Wave w covers d-rows [128w,128w+128); 4-deep register prefetch; two-stage
// LDS reduction; wave w finalizes sample slot w.
// ---------------------------------------------------------------------------
__global__ __launch_bounds__(512) void k1_top(const float* __restrict__ X,
                                              const int* __restrict__ labels,
                                              const float* __restrict__ Wt,
                                              const float* __restrict__ bt,
                                              float* __restrict__ ptop)
{
    __shared__ __align__(16) float sm[12288];  // in_t[1024][12] / red[4][8][232]
    const int tid  = threadIdx.x;
    const int wave = tid >> 6;
    const int lane = tid & 63;
    const int sbase = blockIdx.x * 8;

    for (int idx = tid; idx < 2048; idx += 512) {
        const int j  = idx >> 8;
        const int d4 = idx & 255;
        const float4 v = ((const float4*)&X[(size_t)(sbase + j) * NHID])[d4];
        sm[(4 * d4 + 0) * 12 + j] = v.x;
        sm[(4 * d4 + 1) * 12 + j] = v.y;
        sm[(4 * d4 + 2) * 12 + j] = v.z;
        sm[(4 * d4 + 3) * 12 + j] = v.w;
    }
    __syncthreads();

    float acc[8][4];
#pragma unroll
    for (int j = 0; j < 8; ++j)
#pragma unroll
        for (int k = 0; k < 4; ++k) acc[j][k] = 0.f;

    const int c0 = lane, c1 = lane + 64, c2 = lane + 128, c3 = lane + 192;
    const bool m3 = (c3 < NCLS);
    const int d0 = wave * 128;
    const float* Wr = Wt + (size_t)d0 * NCLS;

    auto ldrow = [&](int r, float* o) {
        const float* p = Wr + (size_t)r * NCLS;
        o[0] = p[c0]; o[1] = p[c1]; o[2] = p[c2];
        o[3] = m3 ? p[c3] : 0.f;
    };
    float wbuf[4][4];
    ldrow(0, wbuf[0]); ldrow(1, wbuf[1]); ldrow(2, wbuf[2]); ldrow(3, wbuf[3]);

#pragma unroll 4
    for (int dd = 0; dd < 128; ++dd) {
        const int slot = dd & 3;
        const float cw0 = wbuf[slot][0], cw1 = wbuf[slot][1],
                    cw2 = wbuf[slot][2], cw3 = wbuf[slot][3];
        ldrow(min(dd + 4, 127), wbuf[slot]);
        const float4 a = *(const float4*)&sm[(d0 + dd) * 12 + 0];
        const float4 b = *(const float4*)&sm[(d0 + dd) * 12 + 4];
        const float xi[8] = {a.x, a.y, a.z, a.w, b.x, b.y, b.z, b.w};
#pragma unroll
        for (int j = 0; j < 8; ++j) {
            acc[j][0] = fmaf(xi[j], cw0, acc[j][0]);
            acc[j][1] = fmaf(xi[j], cw1, acc[j][1]);
            acc[j][2] = fmaf(xi[j], cw2, acc[j][2]);
            acc[j][3] = fmaf(xi[j], cw3, acc[j][3]);
        }
    }
    __syncthreads();

    float* red = sm;   // red[w][j][232]
    if (wave >= 4) {
#pragma unroll
        for (int j = 0; j < 8; ++j)
#pragma unroll
            for (int k = 0; k < 4; ++k) {
                int c = lane + 64 * k;
                if (c < NCLS) red[((wave - 4) * 8 + j) * 232 + c] = acc[j][k];
            }
    }
    __syncthreads();
    if (wave < 4) {
#pragma unroll
        for (int j = 0; j < 8; ++j)
#pragma unroll
            for (int k = 0; k < 4; ++k) {
                int c = lane + 64 * k;
                if (c < NCLS) red[(wave * 8 + j) * 232 + c] += acc[j][k];
            }
    }
    __syncthreads();

    const int j = wave;
    {
        const int s = sbase + j;
        float v[4];
#pragma unroll
        for (int k = 0; k < 4; ++k) {
            int c = lane + 64 * k;
            v[k] = (c < NCLS)
                     ? (red[(0 * 8 + j) * 232 + c] + red[(1 * 8 + j) * 232 + c] +
                        red[(2 * 8 + j) * 232 + c] + red[(3 * 8 + j) * 232 + c] +
                        bt[c])
                     : -INFINITY;
        }
        float m = fmaxf(fmaxf(v[0], v[1]), fmaxf(v[2], v[3]));
        for (int o = 32; o > 0; o >>= 1) m = fmaxf(m, __shfl_xor(m, o));
        float e = expf(v[0] - m) + expf(v[1] - m) + expf(v[2] - m) + expf(v[3] - m);
        for (int o = 32; o > 0; o >>= 1) e += __shfl_xor(e, o);
        const int pt = labels[s] / NPC;
        if (lane == (pt & 63))
            ptop[s] = expf(v[pt >> 6] - m) / e;
    }
}

// ---------------------------------------------------------------------------
// K2: block b = class b (static decomposition, no grouping kernel).
// Self-scan labels -> up to 16 samples per weight pass (single slice stream).
// 512 threads = 8 waves; wave w covers d-rows [128w,128w+128).
// ---------------------------------------------------------------------------
__global__ __launch_bounds__(512) void k2_bottom(const float* __restrict__ X,
                                                 const int* __restrict__ labels,
                                                 const float* __restrict__ Wb,
                                                 const float* __restrict__ bb,
                                                 const float* __restrict__ ptop,
                                                 float* __restrict__ out)
{
    __shared__ __align__(16) float sm[16384];  // in_t[1024][16] / red[4][16][232]
    __shared__ int s_cnt;
    __shared__ int s_ids[64];
    const int cls  = blockIdx.x;
    const int tid  = threadIdx.x;
    const int wave = tid >> 6;
    const int lane = tid & 63;

    if (tid == 0) s_cnt = 0;
    __syncthreads();
    for (int i = tid; i < BATCH; i += 512) {
        if (labels[i] / NPC == cls) {
            int p = atomicAdd(&s_cnt, 1);
            if (p < 64) s_ids[p] = i;
        }
    }
    __syncthreads();
    const int cnt = min(s_cnt, 64);
    if (cnt == 0) return;

    const float* W    = Wb + (size_t)cls * (NHID * NPC);
    const float* bias = bb + (size_t)cls * NPC;

    const int c0 = lane, c1 = lane + 64, c2 = lane + 128, c3 = lane + 192;
    const bool m3 = (c3 < NPC);
    const int d0 = wave * 128;
    const float* Wr = W + (size_t)d0 * NPC;

    for (int base = 0; base < cnt; base += 16) {
        const int nt = min(16, cnt - base);

        // stage up to 16 gathered rows transposed: sm[dd*16 + j]
        for (int idx = tid; idx < 4096; idx += 512) {
            const int j  = idx >> 8;
            const int d4 = idx & 255;
            float4 v = make_float4(0.f, 0.f, 0.f, 0.f);
            if (j < nt) v = ((const float4*)&X[(size_t)s_ids[base + j] * NHID])[d4];
            sm[(4 * d4 + 0) * 16 + j] = v.x;
            sm[(4 * d4 + 1) * 16 + j] = v.y;
            sm[(4 * d4 + 2) * 16 + j] = v.z;
            sm[(4 * d4 + 3) * 16 + j] = v.w;
        }
        __syncthreads();

        float acc[16][4];
#pragma unroll
        for (int j = 0; j < 16; ++j)
#pragma unroll
            for (int k = 0; k < 4; ++k) acc[j][k] = 0.f;

        auto ldrow = [&](int r, float* o) {
            const float* p = Wr + (size_t)r * NPC;
            o[0] = __builtin_nontemporal_load(p + c0);
            o[1] = __builtin_nontemporal_load(p + c1);
            o[2] = __builtin_nontemporal_load(p + c2);
            o[3] = m3 ? __builtin_nontemporal_load(p + c3) : 0.f;
        };
        float wbuf[4][4];
        ldrow(0, wbuf[0]); ldrow(1, wbuf[1]); ldrow(2, wbuf[2]); ldrow(3, wbuf[3]);

#pragma unroll 2
        for (int dd = 0; dd < 128; ++dd) {
            const int slot = dd & 3;
            const float cw0 = wbuf[slot][0], cw1 = wbuf[slot][1],
                        cw2 = wbuf[slot][2], cw3 = wbuf[slot][3];
            ldrow(min(dd + 4, 127), wbuf[slot]);
            const float4 a = *(const float4*)&sm[(d0 + dd) * 16 + 0];
            const float4 b = *(const float4*)&sm[(d0 + dd) * 16 + 4];
            const float c4 = 0.f; (void)c4;
            const float4 c = *(const float4*)&sm[(d0 + dd) * 16 + 8];
            const float4 e = *(const float4*)&sm[(d0 + dd) * 16 + 12];
            const float xi[16] = {a.x, a.y, a.z, a.w, b.x, b.y, b.z, b.w,
                                  c.x, c.y, c.z, c.w, e.x, e.y, e.z, e.w};
#pragma unroll
            for (int j = 0; j < 16; ++j) {
                acc[j][0] = fmaf(xi[j], cw0, acc[j][0]);
                acc[j][1] = fmaf(xi[j], cw1, acc[j][1]);
                acc[j][2] = fmaf(xi[j], cw2, acc[j][2]);
                acc[j][3] = fmaf(xi[j], cw3, acc[j][3]);
            }
        }
        __syncthreads();   // done reading staging

        float* red = sm;   // red[w][j][232], w=0..3, j=0..15
        if (wave >= 4) {
#pragma unroll
            for (int j = 0; j < 16; ++j)
#pragma unroll
                for (int k = 0; k < 4; ++k) {
                    int c = lane + 64 * k;
                    if (c < NPC) red[((wave - 4) * 16 + j) * 232 + c] = acc[j][k];
                }
        }
        __syncthreads();
        if (wave < 4) {
#pragma unroll
            for (int j = 0; j < 16; ++j)
#pragma unroll
                for (int k = 0; k < 4; ++k) {
                    int c = lane + 64 * k;
                    if (c < NPC) red[(wave * 16 + j) * 232 + c] += acc[j][k];
                }
        }
        __syncthreads();

        // finalize: wave w handles slots w and w+8
#pragma unroll
        for (int jj = 0; jj < 2; ++jj) {
            const int j = wave + 8 * jj;
            if (j < nt) {
                const int s = s_ids[base + j];
                float v[4];
#pragma unroll
                for (int k = 0; k < 4; ++k) {
                    int c = lane + 64 * k;
                    v[k] = (c < NPC)
                             ? (red[(0 * 16 + j) * 232 + c] + red[(1 * 16 + j) * 232 + c] +
                                red[(2 * 16 + j) * 232 + c] + red[(3 * 16 + j) * 232 + c] +
                                bias[c])
                             : -INFINITY;
                }
                float m = fmaxf(fmaxf(v[0], v[1]), fmaxf(v[2], v[3]));
                for (int o = 32; o > 0; o >>= 1) m = fmaxf(m, __shfl_xor(m, o));
                float e = expf(v[0] - m) + expf(v[1] - m) + expf(v[2] - m) + expf(v[3] - m);
                for (int o = 32; o > 0; o >>= 1) e += __shfl_xor(e, o);
                const int pb = labels[s] % NPC;
                if (lane == (pb & 63))
                    out[s] = ptop[s] * (expf(v[pb >> 6] - m) / e);
            }
        }
        __syncthreads();   // before next chunk overwrites staging
    }
}

// ---------------------------------------------------------------------------
extern "C" void kernel_launch(void* const* d_in, const int* in_sizes, int n_in,
                              void* d_out, int out_size, void* d_ws, size_t ws_size,
                              hipStream_t stream)
{
    const float* X      = (const float*)d_in[0];
    const int*   labels = (const int*)  d_in[1];
    const float* Wt     = (const float*)d_in[2];
    const float* bt     = (const float*)d_in[3];
    const float* Wb     = (const float*)d_in[4];
    const float* bb     = (const float*)d_in[5];
    float* out  = (float*)d_out;
    float* ptop = (float*)d_ws;

    hipLaunchKernelGGL(k1_top, dim3(BATCH / 8), dim3(512), 0, stream,
                       X, labels, Wt, bt, ptop);
    hipLaunchKernelGGL(k2_bottom, dim3(NCLS), dim3(512), 0, stream,
                       X, labels, Wb, bb, ptop, out);
}

// Round 5
// 325.142 us; speedup vs baseline: 1.0329x; 1.0329x over previous
//
#include <hip/hip_runtime.h>
#include <math.h>

#define NHID 1024
#define NPC  225
#define NCLS 224
#define BATCH 1024

#define MAX_ITEMS 352
#define N_TOP     (BATCH / 8)        // 128
#define GRID_SZ   (1 + N_TOP + MAX_ITEMS)

// ws int-offsets
#define WS_NITEMS 0
#define WS_ORDER  16                 // int order[1024]
#define WS_ITEMS  2048               // int items[352][4] = cls, s0, nt, pad
#define WS_PTOP   4096               // float ptop[1024] (as int bits)
#define WS_DONE   6144               // int done[128]

#define NITEMS_TAG 0x5A5A0000
#define DONE_MAGIC 0x5A5A5A5A

__device__ __forceinline__ void st_rlx(int* p, int v) {
    __hip_atomic_store(p, v, __ATOMIC_RELAXED, __HIP_MEMORY_SCOPE_AGENT);
}
__device__ __forceinline__ int ld_rlx(int* p) {
    return __hip_atomic_load(p, __ATOMIC_RELAXED, __HIP_MEMORY_SCOPE_AGENT);
}

// Single fused kernel:
//   block 0              : grouping (publishes order/items/nitems)
//   blocks 1..128        : top softmax, 8 samples each (publishes ptop + done)
//   blocks 129..480      : bottom items (spin for nitems; spin for ptop at epilogue)
// __launch_bounds__(512,4): VGPR<=128 -> 2 blocks/CU -> all 481 blocks
// co-resident -> spin-waits cannot deadlock regardless of dispatch order.
__global__ __launch_bounds__(512, 4) void hs_fused(
    const float* __restrict__ X, const int* __restrict__ labels,
    const float* __restrict__ Wt, const float* __restrict__ bt,
    const float* __restrict__ Wb, const float* __restrict__ bb,
    int* __restrict__ ws, float* __restrict__ out)
{
    __shared__ __align__(16) float sm[12288];  // in_t[1024][12] / red[4][8][232]
    __shared__ int s_n;
    const int tid  = threadIdx.x;
    const int bid  = blockIdx.x;
    const int wave = tid >> 6;
    const int lane = tid & 63;

    // ================= grouping block =================
    if (bid == 0) {
        int* cnt   = (int*)sm;
        int* scan  = (int*)sm + 256;
        int* iscan = (int*)sm + 512;
        int* cur   = (int*)sm + 768;
        if (tid < 256) cnt[tid] = 0;
        __syncthreads();
        for (int i = tid; i < BATCH; i += 512)
            atomicAdd(&cnt[labels[i] / NPC], 1);
        __syncthreads();
        int myc = 0, myi = 0;
        if (tid < 256) {
            myc = (tid < NCLS) ? cnt[tid] : 0;
            myi = (myc + 7) >> 3;
            scan[tid] = myc; iscan[tid] = myi;
        }
        __syncthreads();
        for (int off = 1; off < 256; off <<= 1) {
            int a = 0, b = 0;
            if (tid < 256 && tid >= off) { a = scan[tid - off]; b = iscan[tid - off]; }
            __syncthreads();
            if (tid < 256) { scan[tid] += a; iscan[tid] += b; }
            __syncthreads();
        }
        if (tid < 256) {
            const int sbase = scan[tid] - myc;
            const int ibase = iscan[tid] - myi;
            cur[tid] = sbase;
            if (tid < NCLS) {
                for (int t = 0; t < myi; ++t) {
                    int* it = ws + WS_ITEMS + 4 * (ibase + t);
                    st_rlx(it + 0, tid);
                    st_rlx(it + 1, sbase + 8 * t);
                    st_rlx(it + 2, min(8, myc - 8 * t));
                }
            }
        }
        __syncthreads();
        for (int i = tid; i < BATCH; i += 512) {
            int c = labels[i] / NPC;
            int p = atomicAdd(&cur[c], 1);
            st_rlx(ws + WS_ORDER + p, i);
        }
        __syncthreads();   // drains all waves' stores before the release-publish
        if (tid == 0)
            __hip_atomic_store(ws + WS_NITEMS, NITEMS_TAG | iscan[255],
                               __ATOMIC_RELEASE, __HIP_MEMORY_SCOPE_AGENT);
        return;
    }

    // ================= top blocks =================
    if (bid <= N_TOP) {
        const int sbase = (bid - 1) * 8;
        for (int idx = tid; idx < 2048; idx += 512) {
            const int j  = idx >> 8;
            const int d4 = idx & 255;
            const float4 v = ((const float4*)&X[(size_t)(sbase + j) * NHID])[d4];
            sm[(4 * d4 + 0) * 12 + j] = v.x;
            sm[(4 * d4 + 1) * 12 + j] = v.y;
            sm[(4 * d4 + 2) * 12 + j] = v.z;
            sm[(4 * d4 + 3) * 12 + j] = v.w;
        }
        __syncthreads();

        float acc[8][4];
#pragma unroll
        for (int j = 0; j < 8; ++j)
#pragma unroll
            for (int k = 0; k < 4; ++k) acc[j][k] = 0.f;

        const int c0 = lane, c1 = lane + 64, c2 = lane + 128, c3 = lane + 192;
        const bool m3 = (c3 < NCLS);
        const int d0 = wave * 128;
        const float* Wr = Wt + (size_t)d0 * NCLS;

        auto ldrow = [&](int r, float* o) {
            const float* p = Wr + (size_t)r * NCLS;
            o[0] = p[c0]; o[1] = p[c1]; o[2] = p[c2];
            o[3] = m3 ? p[c3] : 0.f;
        };
        float wbuf[4][4];
        ldrow(0, wbuf[0]); ldrow(1, wbuf[1]); ldrow(2, wbuf[2]); ldrow(3, wbuf[3]);

#pragma unroll 4
        for (int dd = 0; dd < 128; ++dd) {
            const int slot = dd & 3;
            const float cw0 = wbuf[slot][0], cw1 = wbuf[slot][1],
                        cw2 = wbuf[slot][2], cw3 = wbuf[slot][3];
            ldrow(min(dd + 4, 127), wbuf[slot]);
            const float4 a = *(const float4*)&sm[(d0 + dd) * 12 + 0];
            const float4 b = *(const float4*)&sm[(d0 + dd) * 12 + 4];
            const float xi[8] = {a.x, a.y, a.z, a.w, b.x, b.y, b.z, b.w};
#pragma unroll
            for (int j = 0; j < 8; ++j) {
                acc[j][0] = fmaf(xi[j], cw0, acc[j][0]);
                acc[j][1] = fmaf(xi[j], cw1, acc[j][1]);
                acc[j][2] = fmaf(xi[j], cw2, acc[j][2]);
                acc[j][3] = fmaf(xi[j], cw3, acc[j][3]);
            }
        }
        __syncthreads();

        float* red = sm;
        if (wave >= 4) {
#pragma unroll
            for (int j = 0; j < 8; ++j)
#pragma unroll
                for (int k = 0; k < 4; ++k) {
                    int c = lane + 64 * k;
                    if (c < NCLS) red[((wave - 4) * 8 + j) * 232 + c] = acc[j][k];
                }
        }
        __syncthreads();
        if (wave < 4) {
#pragma unroll
            for (int j = 0; j < 8; ++j)
#pragma unroll
                for (int k = 0; k < 4; ++k) {
                    int c = lane + 64 * k;
                    if (c < NCLS) red[(wave * 8 + j) * 232 + c] += acc[j][k];
                }
        }
        __syncthreads();

        {
            const int j = wave;
            const int s = sbase + j;
            float v[4];
#pragma unroll
            for (int k = 0; k < 4; ++k) {
                int c = lane + 64 * k;
                v[k] = (c < NCLS)
                         ? (red[(0 * 8 + j) * 232 + c] + red[(1 * 8 + j) * 232 + c] +
                            red[(2 * 8 + j) * 232 + c] + red[(3 * 8 + j) * 232 + c] +
                            bt[c])
                         : -INFINITY;
            }
            float m = fmaxf(fmaxf(v[0], v[1]), fmaxf(v[2], v[3]));
            for (int o = 32; o > 0; o >>= 1) m = fmaxf(m, __shfl_xor(m, o));
            float e = expf(v[0] - m) + expf(v[1] - m) + expf(v[2] - m) + expf(v[3] - m);
            for (int o = 32; o > 0; o >>= 1) e += __shfl_xor(e, o);
            const int pt = labels[s] / NPC;
            if (lane == (pt & 63))
                st_rlx(ws + WS_PTOP + s, __float_as_int(expf(v[pt >> 6] - m) / e));
        }
        __syncthreads();   // all 8 ptop stores drained (barrier implies vmcnt(0))
        if (tid == 0)
            __hip_atomic_store(ws + WS_DONE + (bid - 1), DONE_MAGIC,
                               __ATOMIC_RELEASE, __HIP_MEMORY_SCOPE_AGENT);
        return;
    }

    // ================= bottom blocks =================
    if (tid == 0) {
        int dv;
        for (;;) {
            dv = __hip_atomic_load(ws + WS_NITEMS, __ATOMIC_ACQUIRE,
                                   __HIP_MEMORY_SCOPE_AGENT);
            if ((dv & 0xFFFF0000) == NITEMS_TAG) break;
            __builtin_amdgcn_s_sleep(8);
        }
        s_n = dv & 0xFFFF;
    }
    __syncthreads();
    const int bi = bid - 1 - N_TOP;
    if (bi >= s_n) return;

    int* it = ws + WS_ITEMS + 4 * bi;
    const int cls = ld_rlx(it + 0);
    const int s0  = ld_rlx(it + 1);
    const int nt  = ld_rlx(it + 2);

    int s_ids[8];
#pragma unroll
    for (int j = 0; j < 8; ++j)
        s_ids[j] = (j < nt) ? ld_rlx(ws + WS_ORDER + s0 + j) : 0;

    for (int idx = tid; idx < 2048; idx += 512) {
        const int j  = idx >> 8;
        const int d4 = idx & 255;
        float4 v = make_float4(0.f, 0.f, 0.f, 0.f);
        if (j < nt) v = ((const float4*)&X[(size_t)s_ids[j] * NHID])[d4];
        sm[(4 * d4 + 0) * 12 + j] = v.x;
        sm[(4 * d4 + 1) * 12 + j] = v.y;
        sm[(4 * d4 + 2) * 12 + j] = v.z;
        sm[(4 * d4 + 3) * 12 + j] = v.w;
    }
    __syncthreads();

    float acc[8][4];
#pragma unroll
    for (int j = 0; j < 8; ++j)
#pragma unroll
        for (int k = 0; k < 4; ++k) acc[j][k] = 0.f;

    const int c0 = lane, c1 = lane + 64, c2 = lane + 128, c3 = lane + 192;
    const bool m3 = (c3 < NPC);
    const int d0 = wave * 128;
    const float* Wr = Wb + (size_t)cls * (NHID * NPC) + (size_t)d0 * NPC;

    auto ldrow = [&](int r, float* o) {
        const float* p = Wr + (size_t)r * NPC;
        o[0] = __builtin_nontemporal_load(p + c0);
        o[1] = __builtin_nontemporal_load(p + c1);
        o[2] = __builtin_nontemporal_load(p + c2);
        o[3] = m3 ? __builtin_nontemporal_load(p + c3) : 0.f;
    };
    float wbuf[4][4];
    ldrow(0, wbuf[0]); ldrow(1, wbuf[1]); ldrow(2, wbuf[2]); ldrow(3, wbuf[3]);

#pragma unroll 4
    for (int dd = 0; dd < 128; ++dd) {
        const int slot = dd & 3;
        const float cw0 = wbuf[slot][0], cw1 = wbuf[slot][1],
                    cw2 = wbuf[slot][2], cw3 = wbuf[slot][3];
        ldrow(min(dd + 4, 127), wbuf[slot]);
        const float4 a = *(const float4*)&sm[(d0 + dd) * 12 + 0];
        const float4 b = *(const float4*)&sm[(d0 + dd) * 12 + 4];
        const float xi[8] = {a.x, a.y, a.z, a.w, b.x, b.y, b.z, b.w};
#pragma unroll
        for (int j = 0; j < 8; ++j) {
            acc[j][0] = fmaf(xi[j], cw0, acc[j][0]);
            acc[j][1] = fmaf(xi[j], cw1, acc[j][1]);
            acc[j][2] = fmaf(xi[j], cw2, acc[j][2]);
            acc[j][3] = fmaf(xi[j], cw3, acc[j][3]);
        }
    }
    __syncthreads();

    float* red = sm;
    if (wave >= 4) {
#pragma unroll
        for (int j = 0; j < 8; ++j)
#pragma unroll
            for (int k = 0; k < 4; ++k) {
                int c = lane + 64 * k;
                if (c < NPC) red[((wave - 4) * 8 + j) * 232 + c] = acc[j][k];
            }
    }
    __syncthreads();
    if (wave < 4) {
#pragma unroll
        for (int j = 0; j < 8; ++j)
#pragma unroll
            for (int k = 0; k < 4; ++k) {
                int c = lane + 64 * k;
                if (c < NPC) red[(wave * 8 + j) * 232 + c] += acc[j][k];
            }
    }
    __syncthreads();

    {
        const int j = wave;
        if (j < nt) {
            const int s = s_ids[j];
            float v[4];
#pragma unroll
            for (int k = 0; k < 4; ++k) {
                int c = lane + 64 * k;
                v[k] = (c < NPC)
                         ? (red[(0 * 8 + j) * 232 + c] + red[(1 * 8 + j) * 232 + c] +
                            red[(2 * 8 + j) * 232 + c] + red[(3 * 8 + j) * 232 + c] +
                            bb[(size_t)cls * NPC + c])
                         : -INFINITY;
            }
            float m = fmaxf(fmaxf(v[0], v[1]), fmaxf(v[2], v[3]));
            for (int o = 32; o > 0; o >>= 1) m = fmaxf(m, __shfl_xor(m, o));
            float e = expf(v[0] - m) + expf(v[1] - m) + expf(v[2] - m) + expf(v[3] - m);
            for (int o = 32; o > 0; o >>= 1) e += __shfl_xor(e, o);
            const int pb = labels[s] % NPC;
            if (lane == (pb & 63)) {
                int dv;
                for (;;) {
                    dv = __hip_atomic_load(ws + WS_DONE + (s >> 3), __ATOMIC_ACQUIRE,
                                           __HIP_MEMORY_SCOPE_AGENT);
                    if (dv == DONE_MAGIC) break;
                    __builtin_amdgcn_s_sleep(8);
                }
                const float pt = __int_as_float(ld_rlx(ws + WS_PTOP + s));
                out[s] = pt * (expf(v[pb >> 6] - m) / e);
            }
        }
    }
}

// ---------------------------------------------------------------------------
extern "C" void kernel_launch(void* const* d_in, const int* in_sizes, int n_in,
                              void* d_out, int out_size, void* d_ws, size_t ws_size,
                              hipStream_t stream)
{
    const float* X      = (const float*)d_in[0];
    const int*   labels = (const int*)  d_in[1];
    const float* Wt     = (const float*)d_in[2];
    const float* bt     = (const float*)d_in[3];
    const float* Wb     = (const float*)d_in[4];
    const float* bb     = (const float*)d_in[5];

    hipLaunchKernelGGL(hs_fused, dim3(GRID_SZ), dim3(512), 0, stream,
                       X, labels, Wt, bt, Wb, bb, (int*)d_ws, (float*)d_out);
}